// Round 4
// baseline (1582.599 us; speedup 1.0000x reference)
//
#include <hip/hip_runtime.h>

// LSTM_26877905338550 — B=1048576 independent tiny-MLP LSTM chains, T=3.
// R4: R3 + amdgpu_waves_per_eu(3,3). R3 spilled ~30 floats/thread (WRITE
// 122 MB) because the backend targeted ~6 waves/EU (VGPR=84) even though
// 44 KB LDS caps the CU at 3 blocks (3 waves/EU, 168 VGPR budget).
// Pinning waves/EU to 3 gives regalloc the full 168; peak live ~157.

#define NB 1048576

// packed weight offsets (floats), all 16B aligned
#define OWX   0      // Wx   [30][8]
#define OWH   240    // Wh   [30][32] (30 used)
#define OHTB  1200   // ht_b [32]
#define OW0   1232   // W0'  [30][32]
#define OB0   2192   // b0   [32]
#define OW1   2224   // W1   [45][32]
#define OB1   3664   // b1   [48]
#define OW2   3712   // W2   [40][48] (45 used)
#define OB2   5632   // b2   [40]
#define OW3   5672   // W3   [30][40]
#define OB3   6872   // b3   [32]
#define OGW   6904   // gW   [120][32] (30 used)
#define OGB   10744  // gb   [120]
#define OPW   10864  // pW   [32]  (p2@p1 fused)
#define OPB   10896  // pb   scalar
#define WTOT  10912  // padded to float4 multiple

__global__ void prep_kernel(const float* __restrict__ htW, const float* __restrict__ htb,
                            const float* __restrict__ w0,  const float* __restrict__ b0,
                            const float* __restrict__ w1,  const float* __restrict__ b1,
                            const float* __restrict__ w2,  const float* __restrict__ b2,
                            const float* __restrict__ w3,  const float* __restrict__ b3,
                            const float* __restrict__ gw,  const float* __restrict__ gb,
                            const float* __restrict__ p1w, const float* __restrict__ p1b,
                            const float* __restrict__ p2w, const float* __restrict__ p2b,
                            float* __restrict__ ws) {
  int tid = threadIdx.x;
  for (int i = tid; i < 240; i += 256) {            // Wx [30][8]
    int j = i >> 3, k = i & 7;
    ws[OWX + i] = htW[j * 38 + k];
  }
  for (int i = tid; i < 960; i += 256) {            // Wh [30][32]
    int j = i >> 5, k = i & 31;
    ws[OWH + i] = (k < 30) ? htW[j * 38 + 8 + k] : 0.f;
  }
  for (int i = tid; i < 32; i += 256) ws[OHTB + i] = (i < 30) ? htb[i] : 0.f;
  for (int i = tid; i < 960; i += 256) {            // W0' = W0[:, :30] + W0[:, 30:]
    int j = i >> 5, k = i & 31;
    ws[OW0 + i] = (k < 30) ? (w0[j * 60 + k] + w0[j * 60 + 30 + k]) : 0.f;
  }
  for (int i = tid; i < 32; i += 256) ws[OB0 + i] = (i < 30) ? b0[i] : 0.f;
  for (int i = tid; i < 1440; i += 256) {           // W1 [45][32]
    int j = i >> 5, k = i & 31;
    ws[OW1 + i] = (k < 30) ? w1[j * 30 + k] : 0.f;
  }
  for (int i = tid; i < 48; i += 256) ws[OB1 + i] = (i < 45) ? b1[i] : 0.f;
  for (int i = tid; i < 1920; i += 256) {           // W2 [40][48]
    int j = i / 48, k = i % 48;
    ws[OW2 + i] = (k < 45) ? w2[j * 45 + k] : 0.f;
  }
  for (int i = tid; i < 40; i += 256) ws[OB2 + i] = b2[i];
  for (int i = tid; i < 1200; i += 256) {           // W3 [30][40]
    int j = i / 40, k = i % 40;
    ws[OW3 + i] = w3[j * 40 + k];
  }
  for (int i = tid; i < 32; i += 256) ws[OB3 + i] = (i < 30) ? b3[i] : 0.f;
  for (int i = tid; i < 3840; i += 256) {           // gW [120][32]
    int j = i >> 5, k = i & 31;
    ws[OGW + i] = (k < 30) ? gw[j * 30 + k] : 0.f;
  }
  for (int i = tid; i < 120; i += 256) ws[OGB + i] = gb[i];
  for (int i = tid; i < 32; i += 256) {             // pW = p2W @ p1W
    float acc = 0.f;
    if (i < 30)
      for (int m = 0; m < 10; m++) acc += p2w[m] * p1w[m * 30 + i];
    ws[OPW + i] = acc;
  }
  for (int i = tid; i < WTOT - 10897; i += 256) ws[10897 + i] = 0.f;  // pad
  if (tid == 0) {
    float acc = p2b[0];
    for (int m = 0; m < 10; m++) acc += p2w[m] * p1b[m];
    ws[OPB] = acc;
  }
}

__device__ __forceinline__ float ftanh(float v) {
  float u = __builtin_amdgcn_exp2f(v * 2.8853900817779268f);
  return 1.0f - 2.0f * __builtin_amdgcn_rcpf(u + 1.0f);
}
__device__ __forceinline__ float fsigm(float v) {
  float u = __builtin_amdgcn_exp2f(v * -1.4426950408889634f);
  return __builtin_amdgcn_rcpf(1.0f + u);
}

#define SBAR() __builtin_amdgcn_sched_barrier(0)

// out[j] = (TANH? tanh : id)(sum_k W[woff + j*STRIDE + k] * in[k] + W[boff + j])
template <int OUT, int IN, int STRIDE, bool TANH>
__device__ __forceinline__ void layer(const float* Wl, int woff, int boff,
                                      const float* in, float* outv) {
  constexpr int K4 = IN / 4;
#pragma unroll
  for (int j = 0; j < OUT; j++) {
    float acc = Wl[boff + j];
#pragma unroll
    for (int k4 = 0; k4 < K4; k4++) {
      float4 wv = *(const float4*)&Wl[woff + j * STRIDE + k4 * 4];
      acc = fmaf(wv.x, in[k4 * 4 + 0], acc);
      acc = fmaf(wv.y, in[k4 * 4 + 1], acc);
      acc = fmaf(wv.z, in[k4 * 4 + 2], acc);
      acc = fmaf(wv.w, in[k4 * 4 + 3], acc);
    }
    if constexpr ((IN & 3) >= 2) {
      float2 wv = *(const float2*)&Wl[woff + j * STRIDE + K4 * 4];
      acc = fmaf(wv.x, in[K4 * 4 + 0], acc);
      acc = fmaf(wv.y, in[K4 * 4 + 1], acc);
      if constexpr ((IN & 3) == 3)
        acc = fmaf(Wl[woff + j * STRIDE + K4 * 4 + 2], in[K4 * 4 + 2], acc);
    } else if constexpr ((IN & 3) == 1) {
      acc = fmaf(Wl[woff + j * STRIDE + K4 * 4], in[K4 * 4], acc);
    }
    outv[j] = TANH ? ftanh(acc) : acc;
    if ((j & 7) == 7) SBAR();
  }
}

__global__ void __launch_bounds__(256)
__attribute__((amdgpu_waves_per_eu(3, 3)))
lstm_main(const float* __restrict__ x, const float* __restrict__ w,
          float* __restrict__ out) {
  __shared__ __align__(16) float Wl[WTOT];
  int tid = threadIdx.x;
  for (int i = tid; i < WTOT / 4; i += 256)
    ((float4*)Wl)[i] = ((const float4*)w)[i];
  __syncthreads();

  int b = blockIdx.x * 256 + tid;
  const float* xb = x + (size_t)b * 24;

  float hidden[30], cell[30];
#pragma unroll
  for (int j = 0; j < 30; j++) { hidden[j] = 0.f; cell[j] = 0.f; }

  for (int t = 0; t < 3; t++) {  // NOT unrolled: keep code small (I$)
    float4 xa = *(const float4*)(xb + t * 8);
    float4 xc = *(const float4*)(xb + t * 8 + 4);

    // hs = Wx@x_t + Wh@hidden + ht_b  (t=0: skip Wh, hidden==0)
    float hs[30];
#pragma unroll
    for (int j = 0; j < 30; j++) {
      float acc = Wl[OHTB + j];
      float4 wa = *(const float4*)&Wl[OWX + j * 8];
      float4 wc = *(const float4*)&Wl[OWX + j * 8 + 4];
      acc = fmaf(wa.x, xa.x, acc);
      acc = fmaf(wa.y, xa.y, acc);
      acc = fmaf(wa.z, xa.z, acc);
      acc = fmaf(wa.w, xa.w, acc);
      acc = fmaf(wc.x, xc.x, acc);
      acc = fmaf(wc.y, xc.y, acc);
      acc = fmaf(wc.z, xc.z, acc);
      acc = fmaf(wc.w, xc.w, acc);
      if (t > 0) {
#pragma unroll
        for (int k4 = 0; k4 < 7; k4++) {
          float4 wv = *(const float4*)&Wl[OWH + j * 32 + k4 * 4];
          acc = fmaf(wv.x, hidden[k4 * 4 + 0], acc);
          acc = fmaf(wv.y, hidden[k4 * 4 + 1], acc);
          acc = fmaf(wv.z, hidden[k4 * 4 + 2], acc);
          acc = fmaf(wv.w, hidden[k4 * 4 + 3], acc);
        }
        float2 wv = *(const float2*)&Wl[OWH + j * 32 + 28];
        acc = fmaf(wv.x, hidden[28], acc);
        acc = fmaf(wv.y, hidden[29], acc);
      }
      hs[j] = acc;
      if ((j & 7) == 7) SBAR();
    }
    SBAR();
    float a0[30];
    layer<30, 30, 32, true>(Wl, OW0, OB0, hs, a0);
    SBAR();
    float a1[45];
    layer<45, 30, 32, true>(Wl, OW1, OB1, a0, a1);
    SBAR();
    float a2[40];
    layer<40, 45, 48, true>(Wl, OW2, OB2, a1, a2);
    SBAR();
    float a3[30];
    layer<30, 40, 40, true>(Wl, OW3, OB3, a2, a3);
    SBAR();
    // gates + LSTM update
#pragma unroll
    for (int j = 0; j < 30; j++) {
      float d0 = Wl[OGB + j];
      float d1 = Wl[OGB + 30 + j];
      float d2 = Wl[OGB + 60 + j];
      float d3 = Wl[OGB + 90 + j];
#pragma unroll
      for (int k4 = 0; k4 < 7; k4++) {
        float4 wi = *(const float4*)&Wl[OGW + (j)*32 + k4 * 4];
        float4 wf = *(const float4*)&Wl[OGW + (30 + j) * 32 + k4 * 4];
        float4 wo = *(const float4*)&Wl[OGW + (60 + j) * 32 + k4 * 4];
        float4 wg = *(const float4*)&Wl[OGW + (90 + j) * 32 + k4 * 4];
#pragma unroll
        for (int q = 0; q < 4; q++) {
          float a = a3[k4 * 4 + q];
          d0 = fmaf(q == 0 ? wi.x : q == 1 ? wi.y : q == 2 ? wi.z : wi.w, a, d0);
          d1 = fmaf(q == 0 ? wf.x : q == 1 ? wf.y : q == 2 ? wf.z : wf.w, a, d1);
          d2 = fmaf(q == 0 ? wo.x : q == 1 ? wo.y : q == 2 ? wo.z : wo.w, a, d2);
          d3 = fmaf(q == 0 ? wg.x : q == 1 ? wg.y : q == 2 ? wg.z : wg.w, a, d3);
        }
      }
      {
        float2 wi = *(const float2*)&Wl[OGW + (j)*32 + 28];
        float2 wf = *(const float2*)&Wl[OGW + (30 + j) * 32 + 28];
        float2 wo = *(const float2*)&Wl[OGW + (60 + j) * 32 + 28];
        float2 wg = *(const float2*)&Wl[OGW + (90 + j) * 32 + 28];
        d0 = fmaf(wi.x, a3[28], d0); d0 = fmaf(wi.y, a3[29], d0);
        d1 = fmaf(wf.x, a3[28], d1); d1 = fmaf(wf.y, a3[29], d1);
        d2 = fmaf(wo.x, a3[28], d2); d2 = fmaf(wo.y, a3[29], d2);
        d3 = fmaf(wg.x, a3[28], d3); d3 = fmaf(wg.y, a3[29], d3);
      }
      float ig = fsigm(ftanh(d0));
      float fg = fsigm(ftanh(d1));
      float og = fsigm(ftanh(d2));
      float gg = ftanh(ftanh(d3));
      float c = fmaf(fg, cell[j], ig * gg);  // t=0: cell==0, exact
      cell[j] = c;
      hidden[j] = og * ftanh(c);
      if ((j & 3) == 3) SBAR();
    }
    SBAR();
  }
  // out = pW @ hidden + pb
  float acc = Wl[OPB];
#pragma unroll
  for (int k = 0; k < 30; k++) acc = fmaf(Wl[OPW + k], hidden[k], acc);
  out[b] = acc;
}

extern "C" void kernel_launch(void* const* d_in, const int* in_sizes, int n_in,
                              void* d_out, int out_size, void* d_ws, size_t ws_size,
                              hipStream_t stream) {
  const float* x   = (const float*)d_in[0];
  const float* htW = (const float*)d_in[1];
  const float* htb = (const float*)d_in[2];
  const float* w0  = (const float*)d_in[3];
  const float* b0  = (const float*)d_in[4];
  const float* w1  = (const float*)d_in[5];
  const float* b1  = (const float*)d_in[6];
  const float* w2  = (const float*)d_in[7];
  const float* b2  = (const float*)d_in[8];
  const float* w3  = (const float*)d_in[9];
  const float* b3  = (const float*)d_in[10];
  const float* gw  = (const float*)d_in[11];
  const float* gb  = (const float*)d_in[12];
  const float* p1w = (const float*)d_in[13];
  const float* p1b = (const float*)d_in[14];
  const float* p2w = (const float*)d_in[15];
  const float* p2b = (const float*)d_in[16];
  float* ws = (float*)d_ws;
  float* out = (float*)d_out;

  hipLaunchKernelGGL(prep_kernel, dim3(1), dim3(256), 0, stream,
                     htW, htb, w0, b0, w1, b1, w2, b2, w3, b3, gw, gb,
                     p1w, p1b, p2w, p2b, ws);
  hipLaunchKernelGGL(lstm_main, dim3(NB / 256), dim3(256), 0, stream, x, ws, out);
}

// Round 5
// 1501.837 us; speedup vs baseline: 1.0538x; 1.0538x over previous
//
#include <hip/hip_runtime.h>

// LSTM_26877905338550 — B=1048576 independent tiny-MLP LSTM chains, T=3.
// R5: R3 + amdgpu_waves_per_eu(3,3) spelled canonically BEFORE __global__
// (R4's mid-declarator placement didn't bind; VGPR stayed 84 and ~30
// floats/thread spilled -> 118 MB excess WRITE_SIZE). LDS caps occupancy
// at 3 blocks/CU (12 waves), so a 3-wave/EU register budget (170 VGPR)
// is free; peak live ~145 fits -> spills should vanish.

#define NB 1048576

// packed weight offsets (floats), all 16B aligned
#define OWX   0      // Wx   [30][8]
#define OWH   240    // Wh   [30][32] (30 used)
#define OHTB  1200   // ht_b [32]
#define OW0   1232   // W0'  [30][32]
#define OB0   2192   // b0   [32]
#define OW1   2224   // W1   [45][32]
#define OB1   3664   // b1   [48]
#define OW2   3712   // W2   [40][48] (45 used)
#define OB2   5632   // b2   [40]
#define OW3   5672   // W3   [30][40]
#define OB3   6872   // b3   [32]
#define OGW   6904   // gW   [120][32] (30 used)
#define OGB   10744  // gb   [120]
#define OPW   10864  // pW   [32]  (p2@p1 fused)
#define OPB   10896  // pb   scalar
#define WTOT  10912  // padded to float4 multiple

__global__ void prep_kernel(const float* __restrict__ htW, const float* __restrict__ htb,
                            const float* __restrict__ w0,  const float* __restrict__ b0,
                            const float* __restrict__ w1,  const float* __restrict__ b1,
                            const float* __restrict__ w2,  const float* __restrict__ b2,
                            const float* __restrict__ w3,  const float* __restrict__ b3,
                            const float* __restrict__ gw,  const float* __restrict__ gb,
                            const float* __restrict__ p1w, const float* __restrict__ p1b,
                            const float* __restrict__ p2w, const float* __restrict__ p2b,
                            float* __restrict__ ws) {
  int tid = threadIdx.x;
  for (int i = tid; i < 240; i += 256) {            // Wx [30][8]
    int j = i >> 3, k = i & 7;
    ws[OWX + i] = htW[j * 38 + k];
  }
  for (int i = tid; i < 960; i += 256) {            // Wh [30][32]
    int j = i >> 5, k = i & 31;
    ws[OWH + i] = (k < 30) ? htW[j * 38 + 8 + k] : 0.f;
  }
  for (int i = tid; i < 32; i += 256) ws[OHTB + i] = (i < 30) ? htb[i] : 0.f;
  for (int i = tid; i < 960; i += 256) {            // W0' = W0[:, :30] + W0[:, 30:]
    int j = i >> 5, k = i & 31;
    ws[OW0 + i] = (k < 30) ? (w0[j * 60 + k] + w0[j * 60 + 30 + k]) : 0.f;
  }
  for (int i = tid; i < 32; i += 256) ws[OB0 + i] = (i < 30) ? b0[i] : 0.f;
  for (int i = tid; i < 1440; i += 256) {           // W1 [45][32]
    int j = i >> 5, k = i & 31;
    ws[OW1 + i] = (k < 30) ? w1[j * 30 + k] : 0.f;
  }
  for (int i = tid; i < 48; i += 256) ws[OB1 + i] = (i < 45) ? b1[i] : 0.f;
  for (int i = tid; i < 1920; i += 256) {           // W2 [40][48]
    int j = i / 48, k = i % 48;
    ws[OW2 + i] = (k < 45) ? w2[j * 45 + k] : 0.f;
  }
  for (int i = tid; i < 40; i += 256) ws[OB2 + i] = b2[i];
  for (int i = tid; i < 1200; i += 256) {           // W3 [30][40]
    int j = i / 40, k = i % 40;
    ws[OW3 + i] = w3[j * 40 + k];
  }
  for (int i = tid; i < 32; i += 256) ws[OB3 + i] = (i < 30) ? b3[i] : 0.f;
  for (int i = tid; i < 3840; i += 256) {           // gW [120][32]
    int j = i >> 5, k = i & 31;
    ws[OGW + i] = (k < 30) ? gw[j * 30 + k] : 0.f;
  }
  for (int i = tid; i < 120; i += 256) ws[OGB + i] = gb[i];
  for (int i = tid; i < 32; i += 256) {             // pW = p2W @ p1W
    float acc = 0.f;
    if (i < 30)
      for (int m = 0; m < 10; m++) acc += p2w[m] * p1w[m * 30 + i];
    ws[OPW + i] = acc;
  }
  for (int i = tid; i < WTOT - 10897; i += 256) ws[10897 + i] = 0.f;  // pad
  if (tid == 0) {
    float acc = p2b[0];
    for (int m = 0; m < 10; m++) acc += p2w[m] * p1b[m];
    ws[OPB] = acc;
  }
}

__device__ __forceinline__ float ftanh(float v) {
  float u = __builtin_amdgcn_exp2f(v * 2.8853900817779268f);
  return 1.0f - 2.0f * __builtin_amdgcn_rcpf(u + 1.0f);
}
__device__ __forceinline__ float fsigm(float v) {
  float u = __builtin_amdgcn_exp2f(v * -1.4426950408889634f);
  return __builtin_amdgcn_rcpf(1.0f + u);
}

#define SBAR() __builtin_amdgcn_sched_barrier(0)

// out[j] = (TANH? tanh : id)(sum_k W[woff + j*STRIDE + k] * in[k] + W[boff + j])
template <int OUT, int IN, int STRIDE, bool TANH>
__device__ __forceinline__ void layer(const float* Wl, int woff, int boff,
                                      const float* in, float* outv) {
  constexpr int K4 = IN / 4;
#pragma unroll
  for (int j = 0; j < OUT; j++) {
    float acc = Wl[boff + j];
#pragma unroll
    for (int k4 = 0; k4 < K4; k4++) {
      float4 wv = *(const float4*)&Wl[woff + j * STRIDE + k4 * 4];
      acc = fmaf(wv.x, in[k4 * 4 + 0], acc);
      acc = fmaf(wv.y, in[k4 * 4 + 1], acc);
      acc = fmaf(wv.z, in[k4 * 4 + 2], acc);
      acc = fmaf(wv.w, in[k4 * 4 + 3], acc);
    }
    if constexpr ((IN & 3) >= 2) {
      float2 wv = *(const float2*)&Wl[woff + j * STRIDE + K4 * 4];
      acc = fmaf(wv.x, in[K4 * 4 + 0], acc);
      acc = fmaf(wv.y, in[K4 * 4 + 1], acc);
      if constexpr ((IN & 3) == 3)
        acc = fmaf(Wl[woff + j * STRIDE + K4 * 4 + 2], in[K4 * 4 + 2], acc);
    } else if constexpr ((IN & 3) == 1) {
      acc = fmaf(Wl[woff + j * STRIDE + K4 * 4], in[K4 * 4], acc);
    }
    outv[j] = TANH ? ftanh(acc) : acc;
    if ((j & 7) == 7) SBAR();
  }
}

__attribute__((amdgpu_flat_work_group_size(256, 256), amdgpu_waves_per_eu(3, 3)))
__global__ void lstm_main(const float* __restrict__ x, const float* __restrict__ w,
                          float* __restrict__ out) {
  __shared__ __align__(16) float Wl[WTOT];
  int tid = threadIdx.x;
  for (int i = tid; i < WTOT / 4; i += 256)
    ((float4*)Wl)[i] = ((const float4*)w)[i];
  __syncthreads();

  int b = blockIdx.x * 256 + tid;
  const float* xb = x + (size_t)b * 24;

  float hidden[30], cell[30];
#pragma unroll
  for (int j = 0; j < 30; j++) { hidden[j] = 0.f; cell[j] = 0.f; }

  for (int t = 0; t < 3; t++) {  // NOT unrolled: keep code small (I$)
    float4 xa = *(const float4*)(xb + t * 8);
    float4 xc = *(const float4*)(xb + t * 8 + 4);

    // hs = Wx@x_t + Wh@hidden + ht_b  (t=0: skip Wh, hidden==0)
    float hs[30];
#pragma unroll
    for (int j = 0; j < 30; j++) {
      float acc = Wl[OHTB + j];
      float4 wa = *(const float4*)&Wl[OWX + j * 8];
      float4 wc = *(const float4*)&Wl[OWX + j * 8 + 4];
      acc = fmaf(wa.x, xa.x, acc);
      acc = fmaf(wa.y, xa.y, acc);
      acc = fmaf(wa.z, xa.z, acc);
      acc = fmaf(wa.w, xa.w, acc);
      acc = fmaf(wc.x, xc.x, acc);
      acc = fmaf(wc.y, xc.y, acc);
      acc = fmaf(wc.z, xc.z, acc);
      acc = fmaf(wc.w, xc.w, acc);
      if (t > 0) {
#pragma unroll
        for (int k4 = 0; k4 < 7; k4++) {
          float4 wv = *(const float4*)&Wl[OWH + j * 32 + k4 * 4];
          acc = fmaf(wv.x, hidden[k4 * 4 + 0], acc);
          acc = fmaf(wv.y, hidden[k4 * 4 + 1], acc);
          acc = fmaf(wv.z, hidden[k4 * 4 + 2], acc);
          acc = fmaf(wv.w, hidden[k4 * 4 + 3], acc);
        }
        float2 wv = *(const float2*)&Wl[OWH + j * 32 + 28];
        acc = fmaf(wv.x, hidden[28], acc);
        acc = fmaf(wv.y, hidden[29], acc);
      }
      hs[j] = acc;
      if ((j & 7) == 7) SBAR();
    }
    SBAR();
    float a0[30];
    layer<30, 30, 32, true>(Wl, OW0, OB0, hs, a0);
    SBAR();
    float a1[45];
    layer<45, 30, 32, true>(Wl, OW1, OB1, a0, a1);
    SBAR();
    float a2[40];
    layer<40, 45, 48, true>(Wl, OW2, OB2, a1, a2);
    SBAR();
    float a3[30];
    layer<30, 40, 40, true>(Wl, OW3, OB3, a2, a3);
    SBAR();
    // gates + LSTM update
#pragma unroll
    for (int j = 0; j < 30; j++) {
      float d0 = Wl[OGB + j];
      float d1 = Wl[OGB + 30 + j];
      float d2 = Wl[OGB + 60 + j];
      float d3 = Wl[OGB + 90 + j];
#pragma unroll
      for (int k4 = 0; k4 < 7; k4++) {
        float4 wi = *(const float4*)&Wl[OGW + (j)*32 + k4 * 4];
        float4 wf = *(const float4*)&Wl[OGW + (30 + j) * 32 + k4 * 4];
        float4 wo = *(const float4*)&Wl[OGW + (60 + j) * 32 + k4 * 4];
        float4 wg = *(const float4*)&Wl[OGW + (90 + j) * 32 + k4 * 4];
#pragma unroll
        for (int q = 0; q < 4; q++) {
          float a = a3[k4 * 4 + q];
          d0 = fmaf(q == 0 ? wi.x : q == 1 ? wi.y : q == 2 ? wi.z : wi.w, a, d0);
          d1 = fmaf(q == 0 ? wf.x : q == 1 ? wf.y : q == 2 ? wf.z : wf.w, a, d1);
          d2 = fmaf(q == 0 ? wo.x : q == 1 ? wo.y : q == 2 ? wo.z : wo.w, a, d2);
          d3 = fmaf(q == 0 ? wg.x : q == 1 ? wg.y : q == 2 ? wg.z : wg.w, a, d3);
        }
      }
      {
        float2 wi = *(const float2*)&Wl[OGW + (j)*32 + 28];
        float2 wf = *(const float2*)&Wl[OGW + (30 + j) * 32 + 28];
        float2 wo = *(const float2*)&Wl[OGW + (60 + j) * 32 + 28];
        float2 wg = *(const float2*)&Wl[OGW + (90 + j) * 32 + 28];
        d0 = fmaf(wi.x, a3[28], d0); d0 = fmaf(wi.y, a3[29], d0);
        d1 = fmaf(wf.x, a3[28], d1); d1 = fmaf(wf.y, a3[29], d1);
        d2 = fmaf(wo.x, a3[28], d2); d2 = fmaf(wo.y, a3[29], d2);
        d3 = fmaf(wg.x, a3[28], d3); d3 = fmaf(wg.y, a3[29], d3);
      }
      float ig = fsigm(ftanh(d0));
      float fg = fsigm(ftanh(d1));
      float og = fsigm(ftanh(d2));
      float gg = ftanh(ftanh(d3));
      float c = fmaf(fg, cell[j], ig * gg);  // t=0: cell==0, exact
      cell[j] = c;
      hidden[j] = og * ftanh(c);
      if ((j & 3) == 3) SBAR();
    }
    SBAR();
  }
  // out = pW @ hidden + pb
  float acc = Wl[OPB];
#pragma unroll
  for (int k = 0; k < 30; k++) acc = fmaf(Wl[OPW + k], hidden[k], acc);
  out[b] = acc;
}

extern "C" void kernel_launch(void* const* d_in, const int* in_sizes, int n_in,
                              void* d_out, int out_size, void* d_ws, size_t ws_size,
                              hipStream_t stream) {
  const float* x   = (const float*)d_in[0];
  const float* htW = (const float*)d_in[1];
  const float* htb = (const float*)d_in[2];
  const float* w0  = (const float*)d_in[3];
  const float* b0  = (const float*)d_in[4];
  const float* w1  = (const float*)d_in[5];
  const float* b1  = (const float*)d_in[6];
  const float* w2  = (const float*)d_in[7];
  const float* b2  = (const float*)d_in[8];
  const float* w3  = (const float*)d_in[9];
  const float* b3  = (const float*)d_in[10];
  const float* gw  = (const float*)d_in[11];
  const float* gb  = (const float*)d_in[12];
  const float* p1w = (const float*)d_in[13];
  const float* p1b = (const float*)d_in[14];
  const float* p2w = (const float*)d_in[15];
  const float* p2b = (const float*)d_in[16];
  float* ws = (float*)d_ws;
  float* out = (float*)d_out;

  hipLaunchKernelGGL(prep_kernel, dim3(1), dim3(256), 0, stream,
                     htW, htb, w0, b0, w1, b1, w2, b2, w3, b3, gw, gb,
                     p1w, p1b, p2w, p2b, ws);
  hipLaunchKernelGGL(lstm_main, dim3(NB / 256), dim3(256), 0, stream, x, ws, out);
}